// Round 1
// baseline (232.471 us; speedup 1.0000x reference)
//
#include <hip/hip_runtime.h>
#include <math.h>

// LorentzNotGroupNorm, MI355X. x:(64,3136,128) fp32, groups=8.
// Group = 8 consecutive pixels x 128 ch = 4KB; one wave per group.
// lane = 8*p + q: pixel p (0..7), channel block q (0..7), 16 ch/lane (4xfloat4).
// Algebraic collapse: with m = avg*rden (so <m,m>_L = -1):
//   alpha_raw = -<avg,y>_L * rden;  alpha = max(alpha_raw, 1+1e-7)
//   <nomin,nomin>_L = <y,y>_L + 2*alpha*alpha_raw - alpha^2
//   x_T = sc*y + k*avg + coef*e0   (scalars sc,k,coef per pixel)
// This version: pass1 caches {avg[128], sc,k,coef} per group (640 B, L3-resident)
// so pass2 skips the entire core() recompute (fold + LDS + dot + rsum + scalar
// chain) and only does: load x + cache -> u -> epilogue -> store.
// All cached values are bit-identical to what pass2 used to recompute.

constexpr int S_GROUPS = 392;              // spatial groups per batch
constexpr int N_GROUPS = 64 * S_GROUPS;    // 25088
constexpr int CSTRIDE = 160;               // floats/group in cache: 128 avg + 8*float4

__device__ __forceinline__ void wave_lds_fence() {
  // Intra-wave LDS producer->consumer: block store-forwarding and reordering.
  __asm__ volatile("" ::: "memory");
  __builtin_amdgcn_wave_barrier();
  __asm__ volatile("" ::: "memory");
}

__device__ __forceinline__ void rsum8x3(float& a, float& b, float& c) {
#pragma unroll
  for (int m = 1; m <= 4; m <<= 1) {
    a += __shfl_xor(a, m, 64);
    b += __shfl_xor(b, m, 64);
    c += __shfl_xor(c, m, 64);
  }
}

// Pixel-mean fold over lane bits {32,16,8}; lane (p,q) ends with mean
// channels {16q+2p, 16q+2p+1} in (c0,c1).
__device__ __forceinline__ void fold_mean(const float v[16], int lane,
                                          float& c0, float& c1) {
  float a8[8];
  const bool h5 = (lane & 32) != 0;
#pragma unroll
  for (int i = 0; i < 8; ++i) {
    float kp = h5 ? v[i + 8] : v[i];
    float sd = h5 ? v[i] : v[i + 8];
    a8[i] = kp + __shfl_xor(sd, 32, 64);
  }
  float a4[4];
  const bool h4 = (lane & 16) != 0;
#pragma unroll
  for (int i = 0; i < 4; ++i) {
    float kp = h4 ? a8[i + 4] : a8[i];
    float sd = h4 ? a8[i] : a8[i + 4];
    a4[i] = kp + __shfl_xor(sd, 16, 64);
  }
  const bool h3 = (lane & 8) != 0;
  float kp0 = h3 ? a4[2] : a4[0], sd0 = h3 ? a4[0] : a4[2];
  float kp1 = h3 ? a4[3] : a4[1], sd1 = h3 ? a4[1] : a4[3];
  c0 = (kp0 + __shfl_xor(sd0, 8, 64)) * 0.125f;
  c1 = (kp1 + __shfl_xor(sd1, 8, 64)) * 0.125f;
}

struct CoreOut {
  float avg[16];                       // unnormalized pixel-mean (this lane's 16 ch)
  float sc, k, coef;                   // x_T = sc*y + k*avg + coef*e0
  float iaL, dpL, yyE, y0p, avg0;      // reduced scalars (dpL,yyE per pixel-row)
};

// core() also streams the group's {avg, sc,k,coef} to the global cache gc.
__device__ __forceinline__ void core(const float v[16], int lane,
                                     float* __restrict__ smrow,
                                     float* __restrict__ gc, CoreOut& o) {
  const int p = lane >> 3, q = lane & 7;
  float c0, c1;
  fold_mean(v, lane, c0, c1);
  *reinterpret_cast<float2*>(&smrow[q * 16 + p * 2]) = make_float2(c0, c1);
  *reinterpret_cast<float2*>(&gc[q * 16 + p * 2]) = make_float2(c0, c1);
  wave_lds_fence();
#pragma unroll
  for (int j = 0; j < 4; ++j)
    *reinterpret_cast<float4*>(&o.avg[4 * j]) =
        *reinterpret_cast<const float4*>(&smrow[q * 16 + 4 * j]);
  wave_lds_fence();

  float pa = 0.f, pd = 0.f, py = 0.f;
#pragma unroll
  for (int i = 0; i < 16; ++i) {
    pa = fmaf(o.avg[i], o.avg[i], pa);   // -> <avg,avg>_L
    pd = fmaf(o.avg[i], v[i], pd);       // -> <avg,y>_L
    py = fmaf(v[i], v[i], py);           // -> ||y||^2_E
  }
  if (q == 0) {
    pa -= 2.f * o.avg[0] * o.avg[0];
    pd -= 2.f * o.avg[0] * v[0];
  }
  rsum8x3(pa, pd, py);
  o.iaL = pa;
  o.dpL = pd;
  o.yyE = py;
  o.y0p = __shfl(v[0], lane & 56, 64);     // y_p[0]
  o.avg0 = __shfl(o.avg[0], 0, 64);        // avg channel 0

  float rden = rsqrtf(fmaxf(-pa, 1e-8f));
  float a_raw = -pd * rden;
  float alpha = fmaxf(a_raw, 1.f + 1e-7f);
  float t = alpha - 1.f;
  float dist = log1pf(t + sqrtf(t * (alpha + 1.f)));    // arccosh(alpha)
  float yyL = py - 2.f * o.y0p * o.y0p;                 // <y,y>_L
  float inn = fmaxf(yyL + 2.f * alpha * a_raw - alpha * alpha, 1e-8f);
  o.sc = dist * rsqrtf(inn);
  float am = alpha * rden;
  float mean0 = rden * o.avg0;
  float v0 = o.sc * (o.y0p - am * o.avg0);              // x_T time comp pre-transp
  o.coef = -v0 / (1.f + mean0);
  o.k = o.coef * rden - o.sc * am;

  if (q == 0)
    *reinterpret_cast<float4*>(&gc[128 + p * 4]) =
        make_float4(o.sc, o.k, o.coef, 0.f);
}

__device__ __forceinline__ float xt_norm(const CoreOut& A) {
  // ||x_T||_E from scalars: x_T = sc*y + k*avg + coef*e0
  float yavgE = A.dpL + 2.f * A.avg0 * A.y0p;
  float aaE = A.iaL + 2.f * A.avg0 * A.avg0;
  float nsq = A.sc * A.sc * A.yyE + A.k * A.k * aaE + 2.f * A.sc * A.k * yavgE +
              A.coef * A.coef + 2.f * A.coef * (A.sc * A.y0p + A.k * A.avg0);
  return sqrtf(fmaxf(nsq, 0.f));
}

__global__ __launch_bounds__(256) void lngn_pass1(const float* __restrict__ x,
                                                  float* __restrict__ var_part,
                                                  float* __restrict__ cache) {
  __shared__ float sm[4][2][128];
  const int w = threadIdx.x >> 6, lane = threadIdx.x & 63;
  const int p = lane >> 3, q = lane & 7;
  const int wid0 = (blockIdx.x * 4 + w) * 2;   // 2 groups per wave
  const float* b0 = x + (size_t)wid0 * 1024 + p * 128 + q * 16;
  float vA[16], vB[16];
#pragma unroll
  for (int j = 0; j < 4; ++j) {
    *reinterpret_cast<float4*>(&vA[4 * j]) =
        *reinterpret_cast<const float4*>(b0 + 4 * j);
    *reinterpret_cast<float4*>(&vB[4 * j]) =
        *reinterpret_cast<const float4*>(b0 + 1024 + 4 * j);
  }
  CoreOut A, B;
  core(vA, lane, sm[w][0], cache + (size_t)wid0 * CSTRIDE, A);
  core(vB, lane, sm[w][1], cache + (size_t)(wid0 + 1) * CSTRIDE, B);
  float nA = xt_norm(A), nB = xt_norm(B);
  if (q == 0) {
    // transposed layout: var_part[(b*8+p)*392 + s] for coalesced finalize reads
    const int b = wid0 / S_GROUPS;
    const int s = wid0 - b * S_GROUPS;       // wid0 even => wid0+1 same batch
    var_part[(size_t)(b * 8 + p) * S_GROUPS + s] = nA;
    var_part[(size_t)(b * 8 + p) * S_GROUPS + s + 1] = nB;
  }
}

__global__ __launch_bounds__(256) void lngn_finalize(
    const float* __restrict__ var_part, float* __restrict__ var_out) {
  const int wv = (int)((blockIdx.x * 256 + threadIdx.x) >> 6);  // 0..511 = b*8+p
  const int lane = threadIdx.x & 63;
  const float* base = var_part + (size_t)wv * S_GROUPS;
  float s = 0.f;
  for (int s0 = lane; s0 < S_GROUPS; s0 += 64) s += base[s0];
#pragma unroll
  for (int m = 32; m >= 1; m >>= 1) s += __shfl_xor(s, m, 64);
  if (lane == 0) var_out[wv] = s * (1.f / (float)S_GROUPS);
}

__global__ __launch_bounds__(256) void lngn_pass2(
    const float* __restrict__ x, const float* __restrict__ gamma,
    const float* __restrict__ beta, const float* __restrict__ var,
    const float* __restrict__ cache, float* __restrict__ out) {
  const int w = threadIdx.x >> 6, lane = threadIdx.x & 63;
  const int p = lane >> 3, q = lane & 7;
  const int wid = blockIdx.x * 4 + w;
  const size_t base = (size_t)wid * 1024 + p * 128 + q * 16;
  const float* gc = cache + (size_t)wid * CSTRIDE;

  float v[16], av[16], gm[16], bt[16];
#pragma unroll
  for (int j = 0; j < 4; ++j) {
    *reinterpret_cast<float4*>(&v[4 * j]) =
        *reinterpret_cast<const float4*>(x + base + 4 * j);
    *reinterpret_cast<float4*>(&av[4 * j]) =
        *reinterpret_cast<const float4*>(gc + q * 16 + 4 * j);
    *reinterpret_cast<float4*>(&gm[4 * j]) =
        *reinterpret_cast<const float4*>(gamma + q * 16 + 4 * j);
    *reinterpret_cast<float4*>(&bt[4 * j]) =
        *reinterpret_cast<const float4*>(beta + q * 16 + 4 * j);
  }
  const float4 sk = *reinterpret_cast<const float4*>(gc + 128 + p * 4);
  const float sc = sk.x, kk = sk.y, coef = sk.z;

  const int b = wid / S_GROUPS;
  const float s1 = 1.f / (var[b * 8 + p] + 1e-5f);

  float u[16];
  float pe = 0.f, pb = 0.f, pbb = 0.f;
#pragma unroll
  for (int i = 0; i < 16; ++i) {
    float xt = fmaf(sc, v[i], kk * av[i]);
    if (i == 0) xt += (q == 0) ? coef : 0.f;
    u[i] = xt * (gm[i] * s1);
    pe = fmaf(u[i], u[i], pe);          // ||u||^2_E
    pb = fmaf(bt[i], u[i], pb);         // -> <beta,u>_L
    pbb = fmaf(bt[i], bt[i], pbb);      // -> <beta,beta>_L
  }
  if (q == 0) {
    pb -= 2.f * bt[0] * u[0];
    pbb -= 2.f * bt[0] * bt[0];
  }
  rsum8x3(pe, pb, pbb);
  const float u0 = __shfl(u[0], 0, 64);
  const float bt0 = __shfl(bt[0], 0, 64);

  float n = sqrtf(pe);
  float scl = fminf(1.f, 10.f / fmaxf(n, 1e-8f));   // rescale_to_max_euclid
  float c2 = scl * pb / (1.f + bt0);                // transp0 coefficient
  float uuL = pe - 2.f * u0 * u0;                   // <u,u>_L
  // w = scl*u + c2*(beta+e0); <w,w>_L expanded in scalars:
  float innw = scl * scl * uuL + 2.f * scl * c2 * (pb - u0) +
               c2 * c2 * (pbb - 2.f * bt0 - 1.f);
  float nrm = sqrtf(fmaxf(innw, 1e-8f));
  float e = expf(nrm), ie = 1.f / e;
  float chv = 0.5f * (e + ie);
  float isn = (0.5f * (e - ie)) / nrm;
  // out = chv*beta + isn*w = (chv+isn*c2)*beta + (isn*scl)*u + (isn*c2)*e0
  float C1 = chv + isn * c2, C2 = isn * scl, C3 = isn * c2;
  float o16[16];
#pragma unroll
  for (int i = 0; i < 16; ++i) o16[i] = fmaf(C1, bt[i], C2 * u[i]);
  if (q == 0) o16[0] += C3;
  float* ob = out + base;
#pragma unroll
  for (int j = 0; j < 4; ++j)
    *reinterpret_cast<float4*>(ob + 4 * j) =
        *reinterpret_cast<const float4*>(&o16[4 * j]);
}

extern "C" void kernel_launch(void* const* d_in, const int* in_sizes, int n_in,
                              void* d_out, int out_size, void* d_ws,
                              size_t ws_size, hipStream_t stream) {
  const float* x = (const float*)d_in[0];
  const float* gamma = (const float*)d_in[1];
  const float* beta = (const float*)d_in[2];
  float* out = (float*)d_out;
  float* var_part = (float*)d_ws;                      // 25088*8 floats
  float* var_final = var_part + (size_t)N_GROUPS * 8;  // 512 floats
  float* cache = var_final + 512;                      // 25088*160 floats (~16 MB)

  lngn_pass1<<<N_GROUPS / 8, 256, 0, stream>>>(x, var_part, cache);
  lngn_finalize<<<128, 256, 0, stream>>>(var_part, var_final);
  lngn_pass2<<<N_GROUPS / 4, 256, 0, stream>>>(x, gamma, beta, var_final, cache,
                                               out);
}

// Round 2
// 208.637 us; speedup vs baseline: 1.1142x; 1.1142x over previous
//
#include <hip/hip_runtime.h>
#include <math.h>

// LorentzNotGroupNorm, MI355X. x:(64,3136,128) fp32, groups=8.
// Group = 8 consecutive pixels x 128 ch = 4KB; one wave per group.
// pass1 (lane = 8*p + q layout): computes per-pixel scalars
//   x_T = sc*y + k*avg + coef*e0
// and NOW also the per-pixel reductions needed by the epilogue:
//   PE = ||gamma*x_T||^2_E, PB = <beta, gamma*x_T>_L, XT0 = x_T[0]
// cached per group: avg[128] + 8 pixel-bundles{sc,k,coef,PE,PB,XT0,-,-}.
// finalize: var (mean of ||x_T|| over spatial) + the global scalar <beta,beta>_L.
// pass2: FULLY ELEMENTWISE, wave-contiguous loads/stores (lane*16B per
// instruction): per pixel compute A1..A4 from cached reductions, then
//   out_i = A1*beta_i + gamma_i*(A2*x_i + A3*avg_i) (+A4 at ch0).
// No reductions, no LDS, no long chains in pass2.

constexpr int S_GROUPS = 392;              // spatial groups per batch
constexpr int N_GROUPS = 64 * S_GROUPS;    // 25088
constexpr int CSTRIDE = 192;               // floats/group: 128 avg + 8*8 bundle

__device__ __forceinline__ void wave_lds_fence() {
  __asm__ volatile("" ::: "memory");
  __builtin_amdgcn_wave_barrier();
  __asm__ volatile("" ::: "memory");
}

__device__ __forceinline__ void rsum8x3(float& a, float& b, float& c) {
#pragma unroll
  for (int m = 1; m <= 4; m <<= 1) {
    a += __shfl_xor(a, m, 64);
    b += __shfl_xor(b, m, 64);
    c += __shfl_xor(c, m, 64);
  }
}

// Pixel-mean fold over lane bits {32,16,8}; lane (p,q) ends with mean
// channels {16q+2p, 16q+2p+1} in (c0,c1).
__device__ __forceinline__ void fold_mean(const float v[16], int lane,
                                          float& c0, float& c1) {
  float a8[8];
  const bool h5 = (lane & 32) != 0;
#pragma unroll
  for (int i = 0; i < 8; ++i) {
    float kp = h5 ? v[i + 8] : v[i];
    float sd = h5 ? v[i] : v[i + 8];
    a8[i] = kp + __shfl_xor(sd, 32, 64);
  }
  float a4[4];
  const bool h4 = (lane & 16) != 0;
#pragma unroll
  for (int i = 0; i < 4; ++i) {
    float kp = h4 ? a8[i + 4] : a8[i];
    float sd = h4 ? a8[i] : a8[i + 4];
    a4[i] = kp + __shfl_xor(sd, 16, 64);
  }
  const bool h3 = (lane & 8) != 0;
  float kp0 = h3 ? a4[2] : a4[0], sd0 = h3 ? a4[0] : a4[2];
  float kp1 = h3 ? a4[3] : a4[1], sd1 = h3 ? a4[1] : a4[3];
  c0 = (kp0 + __shfl_xor(sd0, 8, 64)) * 0.125f;
  c1 = (kp1 + __shfl_xor(sd1, 8, 64)) * 0.125f;
}

struct CoreOut {
  float avg[16];
  float sc, k, coef;
  float nvar;            // ||x_T||_E for this pixel-row
};

// core: scalars sc,k,coef + xt-pass reductions; q==0 lane writes the
// per-pixel bundle {sc,k,coef,PE,PB,XT0,0,0} to gc[128 + p*8].
__device__ __forceinline__ void core(const float v[16], const float gm[16],
                                     const float bt[16], int lane,
                                     float* __restrict__ smrow,
                                     float* __restrict__ gc, CoreOut& o) {
  const int p = lane >> 3, q = lane & 7;
  float c0, c1;
  fold_mean(v, lane, c0, c1);
  *reinterpret_cast<float2*>(&smrow[q * 16 + p * 2]) = make_float2(c0, c1);
  *reinterpret_cast<float2*>(&gc[q * 16 + p * 2]) = make_float2(c0, c1);
  wave_lds_fence();
#pragma unroll
  for (int j = 0; j < 4; ++j)
    *reinterpret_cast<float4*>(&o.avg[4 * j]) =
        *reinterpret_cast<const float4*>(&smrow[q * 16 + 4 * j]);
  wave_lds_fence();

  float pa = 0.f, pd = 0.f, py = 0.f;
#pragma unroll
  for (int i = 0; i < 16; ++i) {
    pa = fmaf(o.avg[i], o.avg[i], pa);   // -> <avg,avg>_L
    pd = fmaf(o.avg[i], v[i], pd);       // -> <avg,y>_L
    py = fmaf(v[i], v[i], py);           // -> ||y||^2_E
  }
  if (q == 0) {
    pa -= 2.f * o.avg[0] * o.avg[0];
    pd -= 2.f * o.avg[0] * v[0];
  }
  rsum8x3(pa, pd, py);
  const float y0p = __shfl(v[0], lane & 56, 64);    // y_p[0]
  const float avg0 = __shfl(o.avg[0], 0, 64);       // avg channel 0

  float rden = rsqrtf(fmaxf(-pa, 1e-8f));
  float a_raw = -pd * rden;
  float alpha = fmaxf(a_raw, 1.f + 1e-7f);
  float t = alpha - 1.f;
  float dist = log1pf(t + sqrtf(t * (alpha + 1.f)));    // arccosh(alpha)
  float yyL = py - 2.f * y0p * y0p;                     // <y,y>_L
  float inn = fmaxf(yyL + 2.f * alpha * a_raw - alpha * alpha, 1e-8f);
  o.sc = dist * rsqrtf(inn);
  float am = alpha * rden;
  float mean0 = rden * avg0;
  float v0 = o.sc * (y0p - am * avg0);                  // x_T time comp pre-transp
  o.coef = -v0 / (1.f + mean0);
  o.k = o.coef * rden - o.sc * am;

  // xt pass: var-norm + epilogue reductions PE, PB, XT0
  float na = 0.f, pe = 0.f, pb = 0.f, xt0 = 0.f, gx0 = 0.f;
#pragma unroll
  for (int i = 0; i < 16; ++i) {
    float xt = fmaf(o.sc, v[i], o.k * o.avg[i]);
    if (i == 0) xt += (q == 0) ? o.coef : 0.f;
    float gx = gm[i] * xt;
    na = fmaf(xt, xt, na);
    pe = fmaf(gx, gx, pe);
    pb = fmaf(bt[i], gx, pb);
    if (i == 0) { xt0 = xt; gx0 = gx; }
  }
  if (q == 0) pb -= 2.f * bt[0] * gx0;   // Lorentz sign on time component
  rsum8x3(na, pe, pb);
  o.nvar = sqrtf(na);
  if (q == 0) {
    *reinterpret_cast<float4*>(&gc[128 + p * 8]) =
        make_float4(o.sc, o.k, o.coef, pe);
    *reinterpret_cast<float4*>(&gc[128 + p * 8 + 4]) =
        make_float4(pb, xt0, 0.f, 0.f);
  }
}

__global__ __launch_bounds__(256) void lngn_pass1(
    const float* __restrict__ x, const float* __restrict__ gamma,
    const float* __restrict__ beta, float* __restrict__ var_part,
    float* __restrict__ cache) {
  __shared__ float sm[4][2][128];
  const int w = threadIdx.x >> 6, lane = threadIdx.x & 63;
  const int p = lane >> 3, q = lane & 7;
  const int wid0 = (blockIdx.x * 4 + w) * 2;   // 2 groups per wave
  const float* b0 = x + (size_t)wid0 * 1024 + p * 128 + q * 16;
  float vA[16], vB[16], gm[16], bt[16];
#pragma unroll
  for (int j = 0; j < 4; ++j) {
    *reinterpret_cast<float4*>(&vA[4 * j]) =
        *reinterpret_cast<const float4*>(b0 + 4 * j);
    *reinterpret_cast<float4*>(&vB[4 * j]) =
        *reinterpret_cast<const float4*>(b0 + 1024 + 4 * j);
    *reinterpret_cast<float4*>(&gm[4 * j]) =
        *reinterpret_cast<const float4*>(gamma + q * 16 + 4 * j);
    *reinterpret_cast<float4*>(&bt[4 * j]) =
        *reinterpret_cast<const float4*>(beta + q * 16 + 4 * j);
  }
  CoreOut A, B;
  core(vA, gm, bt, lane, sm[w][0], cache + (size_t)wid0 * CSTRIDE, A);
  core(vB, gm, bt, lane, sm[w][1], cache + (size_t)(wid0 + 1) * CSTRIDE, B);
  if (q == 0) {
    // transposed layout: var_part[(b*8+p)*392 + s] for coalesced finalize reads
    const int b = wid0 / S_GROUPS;
    const int s = wid0 - b * S_GROUPS;   // wid0 even => wid0+1 same batch
    var_part[(size_t)(b * 8 + p) * S_GROUPS + s] = A.nvar;
    var_part[(size_t)(b * 8 + p) * S_GROUPS + s + 1] = B.nvar;
  }
}

__global__ __launch_bounds__(256) void lngn_finalize(
    const float* __restrict__ var_part, const float* __restrict__ beta,
    float* __restrict__ var_out) {
  const int wv = (int)((blockIdx.x * 256 + threadIdx.x) >> 6);  // 0..511 = b*8+p
  const int lane = threadIdx.x & 63;
  const float* base = var_part + (size_t)wv * S_GROUPS;
  float s = 0.f;
  for (int s0 = lane; s0 < S_GROUPS; s0 += 64) s += base[s0];
#pragma unroll
  for (int m = 32; m >= 1; m >>= 1) s += __shfl_xor(s, m, 64);
  if (lane == 0) var_out[wv] = s * (1.f / (float)S_GROUPS);

  // one wave additionally computes the global scalar <beta,beta>_L
  if (blockIdx.x == 0 && threadIdx.x < 64) {
    const int l = threadIdx.x;
    float b0v = beta[2 * l], b1v = beta[2 * l + 1];
    float tsum = b0v * b0v + b1v * b1v;
    if (l == 0) tsum -= 2.f * b0v * b0v;
#pragma unroll
    for (int m = 32; m >= 1; m >>= 1) tsum += __shfl_xor(tsum, m, 64);
    if (l == 0) var_out[512] = tsum;
  }
}

__global__ __launch_bounds__(256) void lngn_pass2(
    const float* __restrict__ x, const float* __restrict__ gamma,
    const float* __restrict__ beta, const float* __restrict__ var,
    const float* __restrict__ cache, float* __restrict__ out) {
  const int w = threadIdx.x >> 6, lane = threadIdx.x & 63;
  const int wid = blockIdx.x * 4 + w;
  const float* xb = x + (size_t)wid * 1024;
  const float* gc = cache + (size_t)wid * CSTRIDE;
  const int cl = lane & 31;   // channel-quad index: channels 4*cl..+3
  const int par = lane >> 5;  // pixel parity

  // wave-contiguous loads: instruction j covers bytes [j*1024 + lane*16)
  float4 xv[4];
#pragma unroll
  for (int j = 0; j < 4; ++j)
    xv[j] = *reinterpret_cast<const float4*>(xb + j * 256 + 4 * lane);
  const float4 av = *reinterpret_cast<const float4*>(gc + 4 * cl);
  const float4 gm4 = *reinterpret_cast<const float4*>(gamma + 4 * cl);
  const float4 bt4 = *reinterpret_cast<const float4*>(beta + 4 * cl);

  // per-pixel A-chain (lane computes pixel lane&7; 8-fold redundant)
  const int pix = lane & 7;
  const float4 s0 = *reinterpret_cast<const float4*>(gc + 128 + pix * 8);
  const float4 s1v = *reinterpret_cast<const float4*>(gc + 128 + pix * 8 + 4);
  const float sc = s0.x, kk = s0.y, coef = s0.z, PE = s0.w;
  const float PB = s1v.x, XT0 = s1v.y;
  const int b = wid / S_GROUPS;
  const float varv = var[b * 8 + pix];
  const float pbb = var[512];
  const float bt0 = beta[0], gm0 = gamma[0];

  const float is1 = 1.f / (varv + 1e-5f);
  const float pe = is1 * is1 * PE;
  const float pb = is1 * PB;
  const float u0 = is1 * gm0 * XT0;
  const float n = sqrtf(pe);
  const float scl = fminf(1.f, 10.f / fmaxf(n, 1e-8f));
  const float c2 = scl * pb / (1.f + bt0);
  const float uuL = pe - 2.f * u0 * u0;
  const float innw = scl * scl * uuL + 2.f * scl * c2 * (pb - u0) +
                     c2 * c2 * (pbb - 2.f * bt0 - 1.f);
  const float nrm = sqrtf(fmaxf(innw, 1e-8f));
  const float e = expf(nrm), ie = 1.f / e;
  const float chv = 0.5f * (e + ie);
  const float isn = (0.5f * (e - ie)) / nrm;
  const float A1 = chv + isn * c2;        // * beta_i
  const float Cu = isn * scl * is1;
  const float A2 = Cu * sc;               // * gamma_i * x_i
  const float A3 = Cu * kk;               // * gamma_i * avg_i
  const float A4 = fmaf(Cu * gm0, coef, isn * c2);  // += at channel 0

  float* ob = out + (size_t)wid * 1024;
#pragma unroll
  for (int j = 0; j < 4; ++j) {
    const int sp = 2 * j + par;           // pixel of this lane's j-th quad
    const float a1 = __shfl(A1, sp, 64);
    const float a2 = __shfl(A2, sp, 64);
    const float a3 = __shfl(A3, sp, 64);
    const float a4 = __shfl(A4, sp, 64);
    float4 o4;
    o4.x = fmaf(a1, bt4.x, gm4.x * fmaf(a2, xv[j].x, a3 * av.x));
    o4.y = fmaf(a1, bt4.y, gm4.y * fmaf(a2, xv[j].y, a3 * av.y));
    o4.z = fmaf(a1, bt4.z, gm4.z * fmaf(a2, xv[j].z, a3 * av.z));
    o4.w = fmaf(a1, bt4.w, gm4.w * fmaf(a2, xv[j].w, a3 * av.w));
    if (cl == 0) o4.x += a4;              // channel 0 of this pixel
    *reinterpret_cast<float4*>(ob + j * 256 + 4 * lane) = o4;
  }
}

extern "C" void kernel_launch(void* const* d_in, const int* in_sizes, int n_in,
                              void* d_out, int out_size, void* d_ws,
                              size_t ws_size, hipStream_t stream) {
  const float* x = (const float*)d_in[0];
  const float* gamma = (const float*)d_in[1];
  const float* beta = (const float*)d_in[2];
  float* out = (float*)d_out;
  float* var_part = (float*)d_ws;                      // 512*392 floats
  float* var_final = var_part + (size_t)N_GROUPS * 8;  // 513 floats (last=<b,b>_L)
  float* cache = var_part + 201472;                    // 16B-aligned, ~19.3 MB

  lngn_pass1<<<N_GROUPS / 8, 256, 0, stream>>>(x, gamma, beta, var_part, cache);
  lngn_finalize<<<128, 256, 0, stream>>>(var_part, beta, var_final);
  lngn_pass2<<<N_GROUPS / 4, 256, 0, stream>>>(x, gamma, beta, var_final, cache,
                                               out);
}

// Round 3
// 208.066 us; speedup vs baseline: 1.1173x; 1.0027x over previous
//
#include <hip/hip_runtime.h>
#include <math.h>

// LorentzNotGroupNorm, MI355X. x:(64,3136,128) fp32, groups=8.
// Group = 8 consecutive pixels x 128 ch = 4KB; one wave per group.
// pass1 (lane = 8*p + q compute layout): per-pixel scalars
//   x_T = sc*y + k*avg + coef*e0
// plus per-pixel epilogue reductions PE,PB,XT0 cached per group.
// NEW this round: pass1 global loads are wave-CONTIGUOUS (lane*16B), then
// transposed to the 8p+q layout through LDS with an XOR-swizzled quad index
//   slot(i) = i ^ ((i>>5)&7)   (involution; conflict-free both directions)
// -> 64 line-touches per instruction instead of 256. All downstream math is
// bit-identical (pure data movement).
// pass2: fully elementwise, wave-contiguous (unchanged from last round).

constexpr int S_GROUPS = 392;              // spatial groups per batch
constexpr int N_GROUPS = 64 * S_GROUPS;    // 25088
constexpr int CSTRIDE = 192;               // floats/group: 128 avg + 8*8 bundle

__device__ __forceinline__ void wave_lds_fence() {
  __asm__ volatile("" ::: "memory");
  __builtin_amdgcn_wave_barrier();
  __asm__ volatile("" ::: "memory");
}

__device__ __forceinline__ void rsum8x3(float& a, float& b, float& c) {
#pragma unroll
  for (int m = 1; m <= 4; m <<= 1) {
    a += __shfl_xor(a, m, 64);
    b += __shfl_xor(b, m, 64);
    c += __shfl_xor(c, m, 64);
  }
}

// Pixel-mean fold over lane bits {32,16,8}; lane (p,q) ends with mean
// channels {16q+2p, 16q+2p+1} in (c0,c1).
__device__ __forceinline__ void fold_mean(const float v[16], int lane,
                                          float& c0, float& c1) {
  float a8[8];
  const bool h5 = (lane & 32) != 0;
#pragma unroll
  for (int i = 0; i < 8; ++i) {
    float kp = h5 ? v[i + 8] : v[i];
    float sd = h5 ? v[i] : v[i + 8];
    a8[i] = kp + __shfl_xor(sd, 32, 64);
  }
  float a4[4];
  const bool h4 = (lane & 16) != 0;
#pragma unroll
  for (int i = 0; i < 4; ++i) {
    float kp = h4 ? a8[i + 4] : a8[i];
    float sd = h4 ? a8[i] : a8[i + 4];
    a4[i] = kp + __shfl_xor(sd, 16, 64);
  }
  const bool h3 = (lane & 8) != 0;
  float kp0 = h3 ? a4[2] : a4[0], sd0 = h3 ? a4[0] : a4[2];
  float kp1 = h3 ? a4[3] : a4[1], sd1 = h3 ? a4[1] : a4[3];
  c0 = (kp0 + __shfl_xor(sd0, 8, 64)) * 0.125f;
  c1 = (kp1 + __shfl_xor(sd1, 8, 64)) * 0.125f;
}

struct CoreOut {
  float avg[16];
  float sc, k, coef;
  float nvar;            // ||x_T||_E for this pixel-row
};

// core: scalars sc,k,coef + xt-pass reductions; q==0 lane writes the
// per-pixel bundle {sc,k,coef,PE,PB,XT0,0,0} to gc[128 + p*8].
__device__ __forceinline__ void core(const float v[16], const float gm[16],
                                     const float bt[16], int lane,
                                     float* __restrict__ smrow,
                                     float* __restrict__ gc, CoreOut& o) {
  const int p = lane >> 3, q = lane & 7;
  float c0, c1;
  fold_mean(v, lane, c0, c1);
  *reinterpret_cast<float2*>(&smrow[q * 16 + p * 2]) = make_float2(c0, c1);
  *reinterpret_cast<float2*>(&gc[q * 16 + p * 2]) = make_float2(c0, c1);
  wave_lds_fence();
#pragma unroll
  for (int j = 0; j < 4; ++j)
    *reinterpret_cast<float4*>(&o.avg[4 * j]) =
        *reinterpret_cast<const float4*>(&smrow[q * 16 + 4 * j]);
  wave_lds_fence();

  float pa = 0.f, pd = 0.f, py = 0.f;
#pragma unroll
  for (int i = 0; i < 16; ++i) {
    pa = fmaf(o.avg[i], o.avg[i], pa);   // -> <avg,avg>_L
    pd = fmaf(o.avg[i], v[i], pd);       // -> <avg,y>_L
    py = fmaf(v[i], v[i], py);           // -> ||y||^2_E
  }
  if (q == 0) {
    pa -= 2.f * o.avg[0] * o.avg[0];
    pd -= 2.f * o.avg[0] * v[0];
  }
  rsum8x3(pa, pd, py);
  const float y0p = __shfl(v[0], lane & 56, 64);    // y_p[0]
  const float avg0 = __shfl(o.avg[0], 0, 64);       // avg channel 0

  float rden = rsqrtf(fmaxf(-pa, 1e-8f));
  float a_raw = -pd * rden;
  float alpha = fmaxf(a_raw, 1.f + 1e-7f);
  float t = alpha - 1.f;
  float dist = log1pf(t + sqrtf(t * (alpha + 1.f)));    // arccosh(alpha)
  float yyL = py - 2.f * y0p * y0p;                     // <y,y>_L
  float inn = fmaxf(yyL + 2.f * alpha * a_raw - alpha * alpha, 1e-8f);
  o.sc = dist * rsqrtf(inn);
  float am = alpha * rden;
  float mean0 = rden * avg0;
  float v0 = o.sc * (y0p - am * avg0);                  // x_T time comp pre-transp
  o.coef = -v0 / (1.f + mean0);
  o.k = o.coef * rden - o.sc * am;

  // xt pass: var-norm + epilogue reductions PE, PB, XT0
  float na = 0.f, pe = 0.f, pb = 0.f, xt0 = 0.f, gx0 = 0.f;
#pragma unroll
  for (int i = 0; i < 16; ++i) {
    float xt = fmaf(o.sc, v[i], o.k * o.avg[i]);
    if (i == 0) xt += (q == 0) ? o.coef : 0.f;
    float gx = gm[i] * xt;
    na = fmaf(xt, xt, na);
    pe = fmaf(gx, gx, pe);
    pb = fmaf(bt[i], gx, pb);
    if (i == 0) { xt0 = xt; gx0 = gx; }
  }
  if (q == 0) pb -= 2.f * bt[0] * gx0;   // Lorentz sign on time component
  rsum8x3(na, pe, pb);
  o.nvar = sqrtf(na);
  if (q == 0) {
    *reinterpret_cast<float4*>(&gc[128 + p * 8]) =
        make_float4(o.sc, o.k, o.coef, pe);
    *reinterpret_cast<float4*>(&gc[128 + p * 8 + 4]) =
        make_float4(pb, xt0, 0.f, 0.f);
  }
}

__global__ __launch_bounds__(256) void lngn_pass1(
    const float* __restrict__ x, const float* __restrict__ gamma,
    const float* __restrict__ beta, float* __restrict__ var_part,
    float* __restrict__ cache) {
  __shared__ float4 xbuf[4][2][256];   // 32 KB: per-wave, per-group swizzled tile
  __shared__ float sm[4][2][128];      // 4 KB fold buffer
  const int w = threadIdx.x >> 6, lane = threadIdx.x & 63;
  const int p = lane >> 3, q = lane & 7;
  const int wid0 = (blockIdx.x * 4 + w) * 2;   // 2 groups per wave
  const float* g0 = x + (size_t)wid0 * 1024;

  // 1) wave-contiguous global loads: instruction j covers [j*1KB + lane*16B)
  float4 sA[4], sB[4];
#pragma unroll
  for (int j = 0; j < 4; ++j) {
    sA[j] = *reinterpret_cast<const float4*>(g0 + j * 256 + 4 * lane);
    sB[j] = *reinterpret_cast<const float4*>(g0 + 1024 + j * 256 + 4 * lane);
  }
  // 2) swizzled LDS writes: logical quad d -> slot d ^ ((d>>5)&7)
#pragma unroll
  for (int j = 0; j < 4; ++j) {
    const int d = 64 * j + lane;
    const int s = d ^ ((d >> 5) & 7);
    xbuf[w][0][s] = sA[j];
    xbuf[w][1][s] = sB[j];
  }
  wave_lds_fence();
  // 3) swizzled reads into the 8p+q layout: quad i = p*32+q*4+j -> slot i^p
  float vA[16], vB[16];
#pragma unroll
  for (int j = 0; j < 4; ++j) {
    const int i = p * 32 + q * 4 + j;
    const int s = i ^ p;
    *reinterpret_cast<float4*>(&vA[4 * j]) = xbuf[w][0][s];
    *reinterpret_cast<float4*>(&vB[4 * j]) = xbuf[w][1][s];
  }

  float gm[16], bt[16];
#pragma unroll
  for (int j = 0; j < 4; ++j) {
    *reinterpret_cast<float4*>(&gm[4 * j]) =
        *reinterpret_cast<const float4*>(gamma + q * 16 + 4 * j);
    *reinterpret_cast<float4*>(&bt[4 * j]) =
        *reinterpret_cast<const float4*>(beta + q * 16 + 4 * j);
  }
  CoreOut A, B;
  core(vA, gm, bt, lane, sm[w][0], cache + (size_t)wid0 * CSTRIDE, A);
  core(vB, gm, bt, lane, sm[w][1], cache + (size_t)(wid0 + 1) * CSTRIDE, B);
  if (q == 0) {
    // transposed layout: var_part[(b*8+p)*392 + s] for coalesced finalize reads
    const int b = wid0 / S_GROUPS;
    const int s = wid0 - b * S_GROUPS;   // wid0 even => wid0+1 same batch
    var_part[(size_t)(b * 8 + p) * S_GROUPS + s] = A.nvar;
    var_part[(size_t)(b * 8 + p) * S_GROUPS + s + 1] = B.nvar;
  }
}

__global__ __launch_bounds__(256) void lngn_finalize(
    const float* __restrict__ var_part, const float* __restrict__ beta,
    float* __restrict__ var_out) {
  const int wv = (int)((blockIdx.x * 256 + threadIdx.x) >> 6);  // 0..511 = b*8+p
  const int lane = threadIdx.x & 63;
  const float* base = var_part + (size_t)wv * S_GROUPS;
  float s = 0.f;
  for (int s0 = lane; s0 < S_GROUPS; s0 += 64) s += base[s0];
#pragma unroll
  for (int m = 32; m >= 1; m >>= 1) s += __shfl_xor(s, m, 64);
  if (lane == 0) var_out[wv] = s * (1.f / (float)S_GROUPS);

  // one wave additionally computes the global scalar <beta,beta>_L
  if (blockIdx.x == 0 && threadIdx.x < 64) {
    const int l = threadIdx.x;
    float b0v = beta[2 * l], b1v = beta[2 * l + 1];
    float tsum = b0v * b0v + b1v * b1v;
    if (l == 0) tsum -= 2.f * b0v * b0v;
#pragma unroll
    for (int m = 32; m >= 1; m >>= 1) tsum += __shfl_xor(tsum, m, 64);
    if (l == 0) var_out[512] = tsum;
  }
}

__global__ __launch_bounds__(256) void lngn_pass2(
    const float* __restrict__ x, const float* __restrict__ gamma,
    const float* __restrict__ beta, const float* __restrict__ var,
    const float* __restrict__ cache, float* __restrict__ out) {
  const int w = threadIdx.x >> 6, lane = threadIdx.x & 63;
  const int wid = blockIdx.x * 4 + w;
  const float* xb = x + (size_t)wid * 1024;
  const float* gc = cache + (size_t)wid * CSTRIDE;
  const int cl = lane & 31;   // channel-quad index: channels 4*cl..+3
  const int par = lane >> 5;  // pixel parity

  // wave-contiguous loads: instruction j covers bytes [j*1024 + lane*16)
  float4 xv[4];
#pragma unroll
  for (int j = 0; j < 4; ++j)
    xv[j] = *reinterpret_cast<const float4*>(xb + j * 256 + 4 * lane);
  const float4 av = *reinterpret_cast<const float4*>(gc + 4 * cl);
  const float4 gm4 = *reinterpret_cast<const float4*>(gamma + 4 * cl);
  const float4 bt4 = *reinterpret_cast<const float4*>(beta + 4 * cl);

  // per-pixel A-chain (lane computes pixel lane&7; 8-fold redundant)
  const int pix = lane & 7;
  const float4 s0 = *reinterpret_cast<const float4*>(gc + 128 + pix * 8);
  const float4 s1v = *reinterpret_cast<const float4*>(gc + 128 + pix * 8 + 4);
  const float sc = s0.x, kk = s0.y, coef = s0.z, PE = s0.w;
  const float PB = s1v.x, XT0 = s1v.y;
  const int b = wid / S_GROUPS;
  const float varv = var[b * 8 + pix];
  const float pbb = var[512];
  const float bt0 = beta[0], gm0 = gamma[0];

  const float is1 = 1.f / (varv + 1e-5f);
  const float pe = is1 * is1 * PE;
  const float pb = is1 * PB;
  const float u0 = is1 * gm0 * XT0;
  const float n = sqrtf(pe);
  const float scl = fminf(1.f, 10.f / fmaxf(n, 1e-8f));
  const float c2 = scl * pb / (1.f + bt0);
  const float uuL = pe - 2.f * u0 * u0;
  const float innw = scl * scl * uuL + 2.f * scl * c2 * (pb - u0) +
                     c2 * c2 * (pbb - 2.f * bt0 - 1.f);
  const float nrm = sqrtf(fmaxf(innw, 1e-8f));
  const float e = expf(nrm), ie = 1.f / e;
  const float chv = 0.5f * (e + ie);
  const float isn = (0.5f * (e - ie)) / nrm;
  const float A1 = chv + isn * c2;        // * beta_i
  const float Cu = isn * scl * is1;
  const float A2 = Cu * sc;               // * gamma_i * x_i
  const float A3 = Cu * kk;               // * gamma_i * avg_i
  const float A4 = fmaf(Cu * gm0, coef, isn * c2);  // += at channel 0

  float* ob = out + (size_t)wid * 1024;
#pragma unroll
  for (int j = 0; j < 4; ++j) {
    const int sp = 2 * j + par;           // pixel of this lane's j-th quad
    const float a1 = __shfl(A1, sp, 64);
    const float a2 = __shfl(A2, sp, 64);
    const float a3 = __shfl(A3, sp, 64);
    const float a4 = __shfl(A4, sp, 64);
    float4 o4;
    o4.x = fmaf(a1, bt4.x, gm4.x * fmaf(a2, xv[j].x, a3 * av.x));
    o4.y = fmaf(a1, bt4.y, gm4.y * fmaf(a2, xv[j].y, a3 * av.y));
    o4.z = fmaf(a1, bt4.z, gm4.z * fmaf(a2, xv[j].z, a3 * av.z));
    o4.w = fmaf(a1, bt4.w, gm4.w * fmaf(a2, xv[j].w, a3 * av.w));
    if (cl == 0) o4.x += a4;              // channel 0 of this pixel
    *reinterpret_cast<float4*>(ob + j * 256 + 4 * lane) = o4;
  }
}

extern "C" void kernel_launch(void* const* d_in, const int* in_sizes, int n_in,
                              void* d_out, int out_size, void* d_ws,
                              size_t ws_size, hipStream_t stream) {
  const float* x = (const float*)d_in[0];
  const float* gamma = (const float*)d_in[1];
  const float* beta = (const float*)d_in[2];
  float* out = (float*)d_out;
  float* var_part = (float*)d_ws;                      // 512*392 floats
  float* var_final = var_part + (size_t)N_GROUPS * 8;  // 513 floats (last=<b,b>_L)
  float* cache = var_part + 201472;                    // 16B-aligned, ~19.3 MB

  lngn_pass1<<<N_GROUPS / 8, 256, 0, stream>>>(x, gamma, beta, var_part, cache);
  lngn_finalize<<<128, 256, 0, stream>>>(var_part, beta, var_final);
  lngn_pass2<<<N_GROUPS / 4, 256, 0, stream>>>(x, gamma, beta, var_final, cache,
                                               out);
}